// Round 1
// baseline (26180.942 us; speedup 1.0000x reference)
//
#include <hip/hip_runtime.h>
#include <math.h>

// ============================================================================
// StackedLSTM: 1 LSTM + 3 CALSTM layers, B=32, T=512, DI=H=512.
//
// R1 design: layer-pipelined ticks. At tick tau, layer l computes timestep
// t = tau - l. One kernel launch per tick (515 launches) = global barrier.
// Block b: layer = b>>6, unit-group = b&63 (8 hidden units -> 32/40 m-cols).
// Thread (512/block): b = tid&31 (batch lane), colg = (tid>>5)&7, dh = tid>>8
// (d-half: A = x_t / h_low, B = own h_prev). Each thread: NG cols x 1 batch,
// 512-deep dot over its half; W row loads are 32-lane same-address broadcasts
// so each W element is fetched ONCE per tick (r=1 -> 38 MB/tick HBM floor).
// Activations staged in LDS (XOR-swizzled, conflict-free reads). Gate phase
// fused (256 threads = 8 units x 32 batches).
//
// ws layout (floats): h[4][2][32][512] then c[4][2][32][512] = 1 MB, parity
// double-buffered by tick (p = tau&1 write, q = p^1 read). Zero-init kernel
// runs first (ws is poisoned 0xAA each launch).
// ============================================================================

#define TT 512
#define HH 512
#define BB 32
#define HC (BB*HH)   // 16384 floats per (h or c) state buffer

__device__ __forceinline__ float* hbuf(float* ws, int l, int par){ return ws + (size_t)((l*2+par)  )*HC; }
__device__ __forceinline__ float* cbuf(float* ws, int l, int par){ return ws + (size_t)(8 + l*2+par)*HC; }

__global__ void zero_ws_k(float* __restrict__ ws){
    int i = blockIdx.x*blockDim.x + threadIdx.x;
    const int n = 16*HC;
    for (; i < n; i += gridDim.x*blockDim.x) ws[i] = 0.f;
}

__device__ __forceinline__ float sigm(float v){ return 1.f/(1.f+__expf(-v)); }

// Computes m[cols][batch] partial products into mbuf (two d-half partials).
// NG = gates per unit (4 for base LSTM, 5 for CALSTM). cols = 8 units * NG.
template<int NG>
__device__ __forceinline__ void compute_mat(
    const float* __restrict__ srcA, int strideA,   // x_t rows (stride T*H) or h_low rows (stride H)
    const float* __restrict__ srcB,                // own h_prev rows (stride H)
    const float* __restrict__ wA,                  // L0: w_ih ; CA: ca_w layer base (rows of 2H)
    const float* __restrict__ wB,                  // L0: w_hh ; CA: unused
    int unit0, float4* __restrict__ aT, float* __restrict__ mbuf)
{
    const int tid  = threadIdx.x;
    const int b    = tid & 31;
    const int colg = (tid >> 5) & 7;
    const int dh   = tid >> 8;           // 0: A-half (d<512), 1: B-half (d>=512)

    float4 acc[NG];
#pragma unroll
    for (int j = 0; j < NG; ++j) acc[j] = make_float4(0.f, 0.f, 0.f, 0.f);

    // cidx = colg*NG + j in [0, NG*8); gate g = cidx>>3, unit u = cidx&7.
    const float* rowA[NG];
    const float* rowB[NG];
#pragma unroll
    for (int j = 0; j < NG; ++j){
        const int cidx = colg*NG + j;
        const int row  = (cidx >> 3)*HH + unit0 + (cidx & 7);
        if (NG == 4){ rowA[j] = wA + row*HH;     rowB[j] = wB + row*HH; }
        else        { rowA[j] = wA + row*(2*HH); rowB[j] = rowA[j] + HH; }
    }

    const int d4s = tid & 31;   // staging: d4 index (coalesced global reads)
    const int sb0 = tid >> 5;   // staging: 0..15 -> (section, batch-row)

    for (int sp = 0; sp < 4; ++sp){              // 4 windows of 128 floats per half
#pragma unroll
        for (int r = 0; r < 4; ++r){
            const int sb  = sb0 + r*16;          // 0..63
            const int sec = sb >> 5, bbq = sb & 31;
            const float* src = (sec == 0) ? (srcA + bbq*strideA) : (srcB + bbq*HH);
            const float4 v = *(const float4*)(src + sp*128 + d4s*4);
            aT[sec*1024 + d4s*32 + (bbq ^ d4s ^ (d4s >> 3))] = v;   // swizzled
        }
        __syncthreads();
        const float4* abase = aT + dh*1024;
        const float4* wp[NG];
#pragma unroll
        for (int j = 0; j < NG; ++j)
            wp[j] = (const float4*)((dh ? rowB[j] : rowA[j]) + sp*128);
#pragma unroll 4
        for (int d4 = 0; d4 < 32; ++d4){
            const float4 a4 = abase[d4*32 + (b ^ d4 ^ (d4 >> 3))];  // conflict-free
#pragma unroll
            for (int j = 0; j < NG; ++j){
                const float4 w4 = wp[j][d4];     // 32-lane broadcast load
                acc[j].x = fmaf(w4.x, a4.x, acc[j].x);
                acc[j].y = fmaf(w4.y, a4.y, acc[j].y);
                acc[j].z = fmaf(w4.z, a4.z, acc[j].z);
                acc[j].w = fmaf(w4.w, a4.w, acc[j].w);
            }
        }
        __syncthreads();
    }
#pragma unroll
    for (int j = 0; j < NG; ++j){
        const int cidx = colg*NG + j;
        mbuf[(dh*40 + cidx)*32 + b] = acc[j].x + acc[j].y + acc[j].z + acc[j].w;
    }
}

__global__ __launch_bounds__(512, 2) void lstm_step_k(
    const float* __restrict__ x, const float* __restrict__ w_ih,
    const float* __restrict__ w_hh, const float* __restrict__ b_ih,
    const float* __restrict__ b_hh, const float* __restrict__ ca_w,
    const float* __restrict__ ca_b, float* __restrict__ out,
    float* __restrict__ ws, int tau)
{
    const int layer = blockIdx.x >> 6;
    const int ugrp  = blockIdx.x & 63;
    const int t = tau - layer;
    if (t < 0 || t >= TT) return;            // pipeline edge: block idle
    const int p = tau & 1, q = p ^ 1;
    const int unit0 = ugrp * 8;

    __shared__ float4 aT[2*1024];            // 32 KB: two 128-float windows x 32 rows
    __shared__ float  mbuf[2*40*32];         // 10 KB: two d-half partials

    const float* srcA; int strideA;
    if (layer == 0){ srcA = x + t*HH;              strideA = TT*HH; }
    else           { srcA = hbuf(ws, layer-1, q);  strideA = HH;    }
    const float* srcB = hbuf(ws, layer, q);

    if (layer == 0) compute_mat<4>(srcA, strideA, srcB, w_ih, w_hh, unit0, aT, mbuf);
    else            compute_mat<5>(srcA, strideA, srcB,
                                   ca_w + (size_t)(layer-1)*5*HH*2*HH, nullptr,
                                   unit0, aT, mbuf);
    __syncthreads();

    const int tid = threadIdx.x;
    if (tid < 256){
        const int u  = tid & 7;
        const int bb = tid >> 3;
        const int j  = unit0 + u;
        const int NG = (layer == 0) ? 4 : 5;
        float m[5];
        for (int g = 0; g < NG; ++g){
            const int cidx = g*8 + u;
            m[g] = mbuf[cidx*32 + bb] + mbuf[(40 + cidx)*32 + bb];
        }
        float hval, cval;
        if (layer == 0){
            const float i_ = sigm (m[0] + b_ih[j]       + b_hh[j]);
            const float f_ = sigm (m[1] + b_ih[HH+j]    + b_hh[HH+j]);
            const float g_ = tanhf(m[2] + b_ih[2*HH+j]  + b_hh[2*HH+j]);
            const float o_ = sigm (m[3] + b_ih[3*HH+j]  + b_hh[3*HH+j]);
            const float cp = cbuf(ws, 0, q)[bb*HH + j];
            cval = i_*g_ + f_*cp;
            hval = o_*tanhf(cval);
        } else {
            const float* cbl = ca_b + (layer-1)*5*HH;
            const float mi  = m[0] + cbl[j];
            const float mfp = m[1] + cbl[HH+j];
            const float mfl = m[2] + cbl[2*HH+j];
            const float mu  = m[3] + cbl[3*HH+j];
            const float mo  = m[4] + cbl[4*HH+j];
            const float cp  = cbuf(ws, layer,   q)[bb*HH + j];
            const float clo = cbuf(ws, layer-1, q)[bb*HH + j];
            cval = cp*sigm(mfp + 1.f) + clo*sigm(mfl + 1.f) + tanhf(mu)*sigm(mi);
            hval = sigm(mo)*tanhf(cval);
        }
        hbuf(ws, layer, p)[bb*HH + j] = hval;
        cbuf(ws, layer, p)[bb*HH + j] = cval;
        if (layer == 3){
            const size_t pos = ((size_t)bb*TT + t)*HH + j;
            out[pos]           = hval;                 // hs
            out[8388608 + pos] = cval;                 // cs
            if (t == TT-1){
                out[16777216 + (size_t)bb*HH + j] = hval;  // hs[:, -1]
                out[16793600 + (size_t)bb*HH + j] = cval;  // cs[:, -1]
            }
        }
    }
}

extern "C" void kernel_launch(void* const* d_in, const int* in_sizes, int n_in,
                              void* d_out, int out_size, void* d_ws, size_t ws_size,
                              hipStream_t stream)
{
    const float* x    = (const float*)d_in[0];
    const float* w_ih = (const float*)d_in[1];
    const float* w_hh = (const float*)d_in[2];
    const float* b_ih = (const float*)d_in[3];
    const float* b_hh = (const float*)d_in[4];
    const float* ca_w = (const float*)d_in[5];
    const float* ca_b = (const float*)d_in[6];
    float* out = (float*)d_out;
    float* ws  = (float*)d_ws;

    hipLaunchKernelGGL(zero_ws_k, dim3(64), dim3(256), 0, stream, ws);
    // ticks: tau in [0, T + L - 2] = [0, 514]
    for (int tau = 0; tau < TT + 3; ++tau)
        hipLaunchKernelGGL(lstm_step_k, dim3(256), dim3(512), 0, stream,
                           x, w_ih, w_hh, b_ih, b_hh, ca_w, ca_b, out, ws, tau);
}

// Round 2
// 23018.221 us; speedup vs baseline: 1.1374x; 1.1374x over previous
//
#include <hip/hip_runtime.h>
#include <math.h>

// ============================================================================
// StackedLSTM persistent-kernel R2.
// 1 LSTM + 3 CALSTM layers, B=32, T=512, DI=H=512, 515 pipelined ticks.
//
// - One persistent kernel, 256 blocks x 512 threads. LDS ~145 KB/block forces
//   1 block/CU -> all 256 blocks co-resident on the 256-CU MI355X; manual
//   grid barrier (agent-scope atomics + __threadfence for cross-XCD vis).
// - Block (layer = bx>>6, ub = bx&63) owns units ub*8..+7 of its layer:
//   32 (L0) / 40 (CA) gate-matrix rows, K=1024. Weights converted fp32->f16
//   into LDS ONCE (the R1 killer was re-streaming 38 MB/tick from HBM).
// - Per tick: stage A=[h_low;h_prev] (f16, 64KB) into LDS, MFMA
//   f32_16x16x32_f16 (M=gate-cols, N=batches, K=1024), 8-way K-split over
//   waves, LDS reduce, fused gate phase. h stored f16 (matmul operand),
//   c fp32. Layer-3 gate phase writes hs/cs/h_last/c_last fp32 to d_out.
// - Frag layouts (learn_hip m89/m118): A[m=lane&15][k=(lane>>4)*8+j],
//   B[n=lane&15][k=(lane>>4)*8+j], C/D col(n)=lane&15 row(m)=(lane>>4)*4+reg.
// - LDS rows padded to 1032 f16 (2064 B, 16B-aligned, 4-dword bank shift per
//   row -> 2-way conflicts only = free per m136).
//
// ws layout (bytes): [0,256K) hws f16[4][2][32][512]; [256K,768K) cws
// f32[4][2][32][512]; [768K,+) barrier counters. Zeroed by zero_ws_k.
// ============================================================================

#define TT 512
#define HH 512
#define NBLK 256
#define ROWP 1032                    // padded LDS row length in f16
#define W_OFF 0
#define A_OFF 82560                  // 40*ROWP*2
#define RED_OFF A_OFF                // aliases A region (used after dots done)
#define MF_OFF (A_OFF + 49152)       // after red[8][48][32] f32
#define LDS_BYTES (A_OFF + 66048)    // + A region 32*ROWP*2 = 148608 B

typedef _Float16 half8 __attribute__((ext_vector_type(8)));
typedef float f32x4 __attribute__((ext_vector_type(4)));

__global__ void zero_ws_k(unsigned* __restrict__ ws){
    int i = blockIdx.x*blockDim.x + threadIdx.x;
    for (; i < 196672; i += gridDim.x*blockDim.x) ws[i] = 0u;
}

__device__ __forceinline__ float sigm(float v){ return 1.f/(1.f+__expf(-v)); }

__device__ __forceinline__ void grid_barrier(unsigned* bar){
    __syncthreads();
    if (threadIdx.x == 0){
        __threadfence();   // release: flush this XCD's view of my writes
        unsigned gen = __hip_atomic_load(bar+1, __ATOMIC_RELAXED, __HIP_MEMORY_SCOPE_AGENT);
        unsigned n   = __hip_atomic_fetch_add(bar, 1u, __ATOMIC_ACQ_REL, __HIP_MEMORY_SCOPE_AGENT);
        if (n == NBLK-1){
            __hip_atomic_store(bar,   0u,     __ATOMIC_RELAXED, __HIP_MEMORY_SCOPE_AGENT);
            __hip_atomic_store(bar+1, gen+1u, __ATOMIC_RELEASE, __HIP_MEMORY_SCOPE_AGENT);
        } else {
            while (__hip_atomic_load(bar+1, __ATOMIC_ACQUIRE, __HIP_MEMORY_SCOPE_AGENT) == gen)
                __builtin_amdgcn_s_sleep(1);
        }
        __threadfence();   // acquire: invalidate stale lines before reading
    }
    __syncthreads();
}

// MT = number of 16-row M-tiles (2 for layer 0: 32 cols; 3 for CA: 40 cols,
// rows 40-47 compute garbage that is never read back).
template<int MT>
__device__ void run_loop(const float* __restrict__ x, const float* __restrict__ b_ih,
                         const float* __restrict__ b_hh, const float* __restrict__ ca_b,
                         float* __restrict__ out, float* __restrict__ ws_f,
                         char* lds, int layer, int ub)
{
    const int tid  = threadIdx.x;
    const int lane = tid & 63;
    const int w    = tid >> 6;              // wave id 0..7 = K-quarter
    const int i16  = lane & 15, qq = lane >> 4;
    _Float16* hws = (_Float16*)ws_f;        // [l][p][b][512] f16
    float*    cws = ws_f + 65536;           // [l][p][b][512] f32
    unsigned* bar = (unsigned*)(ws_f + 196608);

    for (int tau = 0; tau < TT + 3; ++tau){
        grid_barrier(bar);
        const int t = tau - layer;
        if (t < 0 || t >= TT) continue;     // edge of pipeline: barrier only
        const int p = tau & 1, q = p ^ 1;

        // ---- stage A = [h_low ; h_prev] (or [x_t ; h_prev] for L0) ----
        {
            const _Float16* hlow  = hws + ((layer-1)*2+q)*16384;
            const _Float16* hprev = hws + (layer*2+q)*16384;
            for (int cidx = tid; cidx < 4096; cidx += 512){   // 4096 chunks of 8 f16
                const int b = cidx >> 7, kc = (cidx & 127) << 3;
                uint4 v;
                if (kc < 512){
                    if (MT == 2){   // layer 0: x_t fp32 -> f16
                        const float* xs = x + ((size_t)b*TT + t)*HH + kc;
                        const float4 a = *(const float4*)xs;
                        const float4 c = *(const float4*)(xs + 4);
                        union { _Float16 h[8]; uint4 u; } pk;
                        pk.h[0]=(_Float16)a.x; pk.h[1]=(_Float16)a.y;
                        pk.h[2]=(_Float16)a.z; pk.h[3]=(_Float16)a.w;
                        pk.h[4]=(_Float16)c.x; pk.h[5]=(_Float16)c.y;
                        pk.h[6]=(_Float16)c.z; pk.h[7]=(_Float16)c.w;
                        v = pk.u;
                    } else {
                        v = *(const uint4*)(hlow + b*512 + kc);
                    }
                } else {
                    v = *(const uint4*)(hprev + b*512 + (kc - 512));
                }
                *(uint4*)(lds + A_OFF + ((size_t)(b*ROWP + kc))*2) = v;
            }
        }
        __syncthreads();

        // ---- MFMA dots: this wave covers K-range [w*128, w*128+128) ----
        f32x4 acc[MT][2];
#pragma unroll
        for (int mt = 0; mt < MT; ++mt){ acc[mt][0] = (f32x4){0,0,0,0}; acc[mt][1] = (f32x4){0,0,0,0}; }
#pragma unroll
        for (int s = 0; s < 4; ++s){
            const int koff = w*128 + s*32 + qq*8;
            half8 bfrag0 = *(const half8*)(lds + A_OFF + ((0*16 + i16)*ROWP + koff)*2);
            half8 bfrag1 = *(const half8*)(lds + A_OFF + ((1*16 + i16)*ROWP + koff)*2);
#pragma unroll
            for (int mt = 0; mt < MT; ++mt){
                half8 afrag = *(const half8*)(lds + W_OFF + ((mt*16 + i16)*ROWP + koff)*2);
                acc[mt][0] = __builtin_amdgcn_mfma_f32_16x16x32_f16(afrag, bfrag0, acc[mt][0], 0, 0, 0);
                acc[mt][1] = __builtin_amdgcn_mfma_f32_16x16x32_f16(afrag, bfrag1, acc[mt][1], 0, 0, 0);
            }
        }
        __syncthreads();            // A region no longer needed; red aliases it

        // ---- write K-partials: red[kq=w][m][n] ----
#pragma unroll
        for (int mt = 0; mt < MT; ++mt)
#pragma unroll
            for (int nt = 0; nt < 2; ++nt)
#pragma unroll
                for (int r = 0; r < 4; ++r){
                    const int m = mt*16 + qq*4 + r, n = nt*16 + i16;
                    *(float*)(lds + RED_OFF + ((w*48 + m)*32 + n)*4) = acc[mt][nt][r];
                }
        __syncthreads();

        // ---- reduce 8 partials -> mfinal[m][n] ----
        const int rows = (MT == 2) ? 32 : 40;
        for (int o = tid; o < rows*32; o += 512){
            const int m = o >> 5, n = o & 31;
            float sm = 0.f;
#pragma unroll
            for (int kq = 0; kq < 8; ++kq)
                sm += *(float*)(lds + RED_OFF + ((kq*48 + m)*32 + n)*4);
            *(float*)(lds + MF_OFF + o*4) = sm;
        }
        __syncthreads();

        // ---- gate phase: 8 units x 32 batches ----
        if (tid < 256){
            const int u = tid & 7, b = tid >> 3, j = ub*8 + u;
            const float* mf = (const float*)(lds + MF_OFF);
            float hval, cval;
            if (MT == 2){   // layer 0: i,f,g,o
                const float mi  = mf[(0*8+u)*32 + b] + b_ih[j]        + b_hh[j];
                const float mff = mf[(1*8+u)*32 + b] + b_ih[512+j]    + b_hh[512+j];
                const float mg  = mf[(2*8+u)*32 + b] + b_ih[1024+j]   + b_hh[1024+j];
                const float mo  = mf[(3*8+u)*32 + b] + b_ih[1536+j]   + b_hh[1536+j];
                const float cp  = cws[(layer*2+q)*16384 + b*512 + j];
                cval = sigm(mi)*tanhf(mg) + sigm(mff)*cp;
                hval = sigm(mo)*tanhf(cval);
            } else {        // CALSTM: i, f_prev, f_low, u, o
                const float* cbl = ca_b + (layer-1)*2560;
                const float mi  = mf[(0*8+u)*32 + b] + cbl[j];
                const float mfp = mf[(1*8+u)*32 + b] + cbl[512+j];
                const float mfl = mf[(2*8+u)*32 + b] + cbl[1024+j];
                const float mu  = mf[(3*8+u)*32 + b] + cbl[1536+j];
                const float mo  = mf[(4*8+u)*32 + b] + cbl[2048+j];
                const float cp  = cws[(layer*2+q)*16384     + b*512 + j];
                const float clo = cws[((layer-1)*2+q)*16384 + b*512 + j];
                cval = cp*sigm(mfp + 1.f) + clo*sigm(mfl + 1.f) + tanhf(mu)*sigm(mi);
                hval = sigm(mo)*tanhf(cval);
            }
            hws[(layer*2+p)*16384 + b*512 + j] = (_Float16)hval;
            cws[(layer*2+p)*16384 + b*512 + j] = cval;
            if (layer == 3){
                const size_t pos = ((size_t)b*TT + t)*HH + j;
                out[pos]           = hval;
                out[8388608 + pos] = cval;
                if (t == TT-1){
                    out[16777216 + (size_t)b*HH + j] = hval;
                    out[16793600 + (size_t)b*HH + j] = cval;
                }
            }
        }
        // next tick's staging is ordered after gates by grid_barrier's entry
        // __syncthreads (mfinal aliases the A region).
    }
}

__global__ __launch_bounds__(512) void persist_k(
    const float* __restrict__ x, const float* __restrict__ w_ih,
    const float* __restrict__ w_hh, const float* __restrict__ b_ih,
    const float* __restrict__ b_hh, const float* __restrict__ ca_w,
    const float* __restrict__ ca_b, float* __restrict__ out,
    float* __restrict__ ws_f)
{
    extern __shared__ char lds[];
    const int layer = blockIdx.x >> 6, ub = blockIdx.x & 63;
    const int tid = threadIdx.x;
    const int rows = (layer == 0) ? 32 : 40;

    // one-time: weights fp32 -> f16 into LDS. local row r=g*8+u maps to
    // global gate-matrix row g*512 + ub*8 + u.
    for (int idx = tid; idx < rows*256; idx += 512){
        const int r = idx >> 8, k4 = (idx & 255) * 4;
        const int g = r >> 3, u = r & 7;
        const int grow = g*512 + ub*8 + u;
        const float* src;
        if (layer == 0) src = (k4 < 512) ? (w_ih + (size_t)grow*512 + k4)
                                         : (w_hh + (size_t)grow*512 + (k4 - 512));
        else            src = ca_w + (size_t)(layer-1)*2560*1024 + (size_t)grow*1024 + k4;
        const float4 v = *(const float4*)src;
        union { _Float16 h[4]; uint2 u2; } pk;
        pk.h[0]=(_Float16)v.x; pk.h[1]=(_Float16)v.y;
        pk.h[2]=(_Float16)v.z; pk.h[3]=(_Float16)v.w;
        *(uint2*)(lds + W_OFF + ((size_t)(r*ROWP + k4))*2) = pk.u2;
    }
    // first grid_barrier's __syncthreads orders weight-load before use.
    if (layer == 0) run_loop<2>(x, b_ih, b_hh, ca_b, out, ws_f, lds, layer, ub);
    else            run_loop<3>(x, b_ih, b_hh, ca_b, out, ws_f, lds, layer, ub);
}

extern "C" void kernel_launch(void* const* d_in, const int* in_sizes, int n_in,
                              void* d_out, int out_size, void* d_ws, size_t ws_size,
                              hipStream_t stream)
{
    const float* x    = (const float*)d_in[0];
    const float* w_ih = (const float*)d_in[1];
    const float* w_hh = (const float*)d_in[2];
    const float* b_ih = (const float*)d_in[3];
    const float* b_hh = (const float*)d_in[4];
    const float* ca_w = (const float*)d_in[5];
    const float* ca_b = (const float*)d_in[6];
    float* out = (float*)d_out;
    float* ws  = (float*)d_ws;

    (void)hipFuncSetAttribute((const void*)persist_k,
                              hipFuncAttributeMaxDynamicSharedMemorySize, LDS_BYTES);
    hipLaunchKernelGGL(zero_ws_k, dim3(64), dim3(256), 0, stream, (unsigned*)ws);
    hipLaunchKernelGGL(persist_k, dim3(256), dim3(512), LDS_BYTES, stream,
                       x, w_ih, w_hh, b_ih, b_hh, ca_w, ca_b, out, ws);
}

// Round 3
// 9707.959 us; speedup vs baseline: 2.6969x; 2.3711x over previous
//
#include <hip/hip_runtime.h>
#include <math.h>

// ============================================================================
// StackedLSTM persistent-kernel R3.
// Identical to R2 except the grid barrier: R2's single-counter atomic-RMW
// barrier collapsed under contention (256 serialized RMWs + 255 spinners on
// ONE cache line -> ~44 us/tick, VALUBusy 1.7%). R3 uses a flag barrier:
//   arrive : block bx stores gen to its own 64B-strided slot (no RMW)
//   gather : block 0 wave 0 polls all 256 slots (4 lane-parallel loads/round)
//   release: master writes 8 strided words; block bx spins on rel[bx&7]
// Fences preserve the producer->master->consumer happens-before chain.
//
// ws layout (32-bit words):
//   [0,      65536)  hws  f16[4][2][32][512]   (256 KB)
//   [65536, 196608)  cws  f32[4][2][32][512]   (512 KB)
//   [196608,200704)  arrival slots, 256 x 16-word stride (64 B each)
//   [200704,200832)  release words, 8 x 16-word stride
// ============================================================================

#define TT 512
#define HH 512
#define NBLK 256
#define ROWP 1032                    // padded LDS row length in f16
#define W_OFF 0
#define A_OFF 82560                  // 40*ROWP*2
#define RED_OFF A_OFF                // aliases A region (used after dots done)
#define MF_OFF (A_OFF + 49152)       // after red[8][48][32] f32
#define LDS_BYTES (A_OFF + 66048)    // + A region 32*ROWP*2 = 148608 B

#define SLOT_OFF 196608
#define REL_OFF  (196608 + 256*16)
#define WS_ZERO_WORDS (REL_OFF + 8*16)

typedef _Float16 half8 __attribute__((ext_vector_type(8)));
typedef float f32x4 __attribute__((ext_vector_type(4)));

__global__ void zero_ws_k(unsigned* __restrict__ ws){
    int i = blockIdx.x*blockDim.x + threadIdx.x;
    for (; i < WS_ZERO_WORDS; i += gridDim.x*blockDim.x) ws[i] = 0u;
}

__device__ __forceinline__ float sigm(float v){ return 1.f/(1.f+__expf(-v)); }

// Flag-based grid barrier. need = tau+1 (monotone, no wraparound in 515 ticks).
__device__ __forceinline__ void grid_barrier(unsigned* ws_u, int bx, unsigned need){
    unsigned* slots = ws_u + SLOT_OFF;
    unsigned* rel   = ws_u + REL_OFF;
    __syncthreads();
    const int tid = threadIdx.x;
    if (bx == 0){
        if (tid < 64){
            if (tid == 0){
                __threadfence();            // release my block's writes
                __hip_atomic_store(slots, need, __ATOMIC_RELAXED, __HIP_MEMORY_SCOPE_AGENT);
            }
            for (;;){
                const unsigned v0 = __hip_atomic_load(slots + (tid      )*16, __ATOMIC_RELAXED, __HIP_MEMORY_SCOPE_AGENT);
                const unsigned v1 = __hip_atomic_load(slots + (tid +  64)*16, __ATOMIC_RELAXED, __HIP_MEMORY_SCOPE_AGENT);
                const unsigned v2 = __hip_atomic_load(slots + (tid + 128)*16, __ATOMIC_RELAXED, __HIP_MEMORY_SCOPE_AGENT);
                const unsigned v3 = __hip_atomic_load(slots + (tid + 192)*16, __ATOMIC_RELAXED, __HIP_MEMORY_SCOPE_AGENT);
                const int ok = (v0 >= need) & (v1 >= need) & (v2 >= need) & (v3 >= need);
                if (__all(ok)) break;
                __builtin_amdgcn_s_sleep(1);
            }
            __threadfence();                // acquire arrivals / release for rel
            if (tid < 8)
                __hip_atomic_store(rel + tid*16, need, __ATOMIC_RELAXED, __HIP_MEMORY_SCOPE_AGENT);
            __threadfence();
        }
    } else {
        if (tid == 0){
            __threadfence();                // release my block's writes
            __hip_atomic_store(slots + bx*16, need, __ATOMIC_RELAXED, __HIP_MEMORY_SCOPE_AGENT);
            unsigned* myrel = rel + (bx & 7)*16;
            while (__hip_atomic_load(myrel, __ATOMIC_RELAXED, __HIP_MEMORY_SCOPE_AGENT) < need)
                __builtin_amdgcn_s_sleep(1);
            __threadfence();                // acquire everyone's writes
        }
    }
    __syncthreads();
}

// MT = number of 16-row M-tiles (2 for layer 0: 32 cols; 3 for CA: 40 cols,
// rows 40-47 compute garbage that is never read back).
template<int MT>
__device__ void run_loop(const float* __restrict__ x, const float* __restrict__ b_ih,
                         const float* __restrict__ b_hh, const float* __restrict__ ca_b,
                         float* __restrict__ out, float* __restrict__ ws_f,
                         char* lds, int layer, int ub, int bx)
{
    const int tid  = threadIdx.x;
    const int lane = tid & 63;
    const int w    = tid >> 6;              // wave id 0..7 = K-eighth
    const int i16  = lane & 15, qq = lane >> 4;
    _Float16* hws = (_Float16*)ws_f;        // [l][p][b][512] f16
    float*    cws = ws_f + 65536;           // [l][p][b][512] f32
    unsigned* ws_u = (unsigned*)ws_f;

    for (int tau = 0; tau < TT + 3; ++tau){
        grid_barrier(ws_u, bx, (unsigned)(tau + 1));
        const int t = tau - layer;
        if (t < 0 || t >= TT) continue;     // edge of pipeline: barrier only
        const int p = tau & 1, q = p ^ 1;

        // ---- stage A = [h_low ; h_prev] (or [x_t ; h_prev] for L0) ----
        {
            const _Float16* hlow  = hws + ((layer-1)*2+q)*16384;
            const _Float16* hprev = hws + (layer*2+q)*16384;
#pragma unroll
            for (int it = 0; it < 8; ++it){
                const int cidx = tid + it*512;          // 4096 chunks of 8 f16
                const int b = cidx >> 7, kc = (cidx & 127) << 3;
                uint4 v;
                if (kc < 512){
                    if (MT == 2){   // layer 0: x_t fp32 -> f16
                        const float* xs = x + ((size_t)b*TT + t)*HH + kc;
                        const float4 a = *(const float4*)xs;
                        const float4 c = *(const float4*)(xs + 4);
                        union { _Float16 h[8]; uint4 u; } pk;
                        pk.h[0]=(_Float16)a.x; pk.h[1]=(_Float16)a.y;
                        pk.h[2]=(_Float16)a.z; pk.h[3]=(_Float16)a.w;
                        pk.h[4]=(_Float16)c.x; pk.h[5]=(_Float16)c.y;
                        pk.h[6]=(_Float16)c.z; pk.h[7]=(_Float16)c.w;
                        v = pk.u;
                    } else {
                        v = *(const uint4*)(hlow + b*512 + kc);
                    }
                } else {
                    v = *(const uint4*)(hprev + b*512 + (kc - 512));
                }
                *(uint4*)(lds + A_OFF + ((size_t)(b*ROWP + kc))*2) = v;
            }
        }
        __syncthreads();

        // ---- MFMA dots: this wave covers K-range [w*128, w*128+128) ----
        f32x4 acc[MT][2];
#pragma unroll
        for (int mt = 0; mt < MT; ++mt){ acc[mt][0] = (f32x4){0,0,0,0}; acc[mt][1] = (f32x4){0,0,0,0}; }
#pragma unroll
        for (int s = 0; s < 4; ++s){
            const int koff = w*128 + s*32 + qq*8;
            half8 bfrag0 = *(const half8*)(lds + A_OFF + ((0*16 + i16)*ROWP + koff)*2);
            half8 bfrag1 = *(const half8*)(lds + A_OFF + ((1*16 + i16)*ROWP + koff)*2);
#pragma unroll
            for (int mt = 0; mt < MT; ++mt){
                half8 afrag = *(const half8*)(lds + W_OFF + ((mt*16 + i16)*ROWP + koff)*2);
                acc[mt][0] = __builtin_amdgcn_mfma_f32_16x16x32_f16(afrag, bfrag0, acc[mt][0], 0, 0, 0);
                acc[mt][1] = __builtin_amdgcn_mfma_f32_16x16x32_f16(afrag, bfrag1, acc[mt][1], 0, 0, 0);
            }
        }
        __syncthreads();            // A region no longer needed; red aliases it

        // ---- write K-partials: red[kq=w][m][n] ----
#pragma unroll
        for (int mt = 0; mt < MT; ++mt)
#pragma unroll
            for (int nt = 0; nt < 2; ++nt)
#pragma unroll
                for (int r = 0; r < 4; ++r){
                    const int m = mt*16 + qq*4 + r, n = nt*16 + i16;
                    *(float*)(lds + RED_OFF + ((w*48 + m)*32 + n)*4) = acc[mt][nt][r];
                }
        __syncthreads();

        // ---- reduce 8 partials -> mfinal[m][n] ----
        const int rows = (MT == 2) ? 32 : 40;
        for (int o = tid; o < rows*32; o += 512){
            const int m = o >> 5, n = o & 31;
            float sm = 0.f;
#pragma unroll
            for (int kq = 0; kq < 8; ++kq)
                sm += *(float*)(lds + RED_OFF + ((kq*48 + m)*32 + n)*4);
            *(float*)(lds + MF_OFF + o*4) = sm;
        }
        __syncthreads();

        // ---- gate phase: 8 units x 32 batches ----
        if (tid < 256){
            const int u = tid & 7, b = tid >> 3, j = ub*8 + u;
            const float* mf = (const float*)(lds + MF_OFF);
            float hval, cval;
            if (MT == 2){   // layer 0: i,f,g,o
                const float mi  = mf[(0*8+u)*32 + b] + b_ih[j]        + b_hh[j];
                const float mff = mf[(1*8+u)*32 + b] + b_ih[512+j]    + b_hh[512+j];
                const float mg  = mf[(2*8+u)*32 + b] + b_ih[1024+j]   + b_hh[1024+j];
                const float mo  = mf[(3*8+u)*32 + b] + b_ih[1536+j]   + b_hh[1536+j];
                const float cp  = cws[(layer*2+q)*16384 + b*512 + j];
                cval = sigm(mi)*tanhf(mg) + sigm(mff)*cp;
                hval = sigm(mo)*tanhf(cval);
            } else {        // CALSTM: i, f_prev, f_low, u, o
                const float* cbl = ca_b + (layer-1)*2560;
                const float mi  = mf[(0*8+u)*32 + b] + cbl[j];
                const float mfp = mf[(1*8+u)*32 + b] + cbl[512+j];
                const float mfl = mf[(2*8+u)*32 + b] + cbl[1024+j];
                const float mu  = mf[(3*8+u)*32 + b] + cbl[1536+j];
                const float mo  = mf[(4*8+u)*32 + b] + cbl[2048+j];
                const float cp  = cws[(layer*2+q)*16384     + b*512 + j];
                const float clo = cws[((layer-1)*2+q)*16384 + b*512 + j];
                cval = cp*sigm(mfp + 1.f) + clo*sigm(mfl + 1.f) + tanhf(mu)*sigm(mi);
                hval = sigm(mo)*tanhf(cval);
            }
            hws[(layer*2+p)*16384 + b*512 + j] = (_Float16)hval;
            cws[(layer*2+p)*16384 + b*512 + j] = cval;
            if (layer == 3){
                const size_t pos = ((size_t)b*TT + t)*HH + j;
                out[pos]           = hval;
                out[8388608 + pos] = cval;
                if (t == TT-1){
                    out[16777216 + (size_t)b*HH + j] = hval;
                    out[16793600 + (size_t)b*HH + j] = cval;
                }
            }
        }
        // next tick's staging is ordered after gates by grid_barrier's entry
        // __syncthreads (mfinal aliases the A region).
    }
}

__global__ __launch_bounds__(512) void persist_k(
    const float* __restrict__ x, const float* __restrict__ w_ih,
    const float* __restrict__ w_hh, const float* __restrict__ b_ih,
    const float* __restrict__ b_hh, const float* __restrict__ ca_w,
    const float* __restrict__ ca_b, float* __restrict__ out,
    float* __restrict__ ws_f)
{
    extern __shared__ char lds[];
    const int bx = blockIdx.x;
    const int layer = bx >> 6, ub = bx & 63;
    const int tid = threadIdx.x;
    const int rows = (layer == 0) ? 32 : 40;

    // one-time: weights fp32 -> f16 into LDS. local row r=g*8+u maps to
    // global gate-matrix row g*512 + ub*8 + u.
    for (int idx = tid; idx < rows*256; idx += 512){
        const int r = idx >> 8, k4 = (idx & 255) * 4;
        const int g = r >> 3, u = r & 7;
        const int grow = g*512 + ub*8 + u;
        const float* src;
        if (layer == 0) src = (k4 < 512) ? (w_ih + (size_t)grow*512 + k4)
                                         : (w_hh + (size_t)grow*512 + (k4 - 512));
        else            src = ca_w + (size_t)(layer-1)*2560*1024 + (size_t)grow*1024 + k4;
        const float4 v = *(const float4*)src;
        union { _Float16 h[4]; uint2 u2; } pk;
        pk.h[0]=(_Float16)v.x; pk.h[1]=(_Float16)v.y;
        pk.h[2]=(_Float16)v.z; pk.h[3]=(_Float16)v.w;
        *(uint2*)(lds + W_OFF + ((size_t)(r*ROWP + k4))*2) = pk.u2;
    }
    // first grid_barrier's __syncthreads orders weight-load before use.
    if (layer == 0) run_loop<2>(x, b_ih, b_hh, ca_b, out, ws_f, lds, layer, ub, bx);
    else            run_loop<3>(x, b_ih, b_hh, ca_b, out, ws_f, lds, layer, ub, bx);
}

extern "C" void kernel_launch(void* const* d_in, const int* in_sizes, int n_in,
                              void* d_out, int out_size, void* d_ws, size_t ws_size,
                              hipStream_t stream)
{
    const float* x    = (const float*)d_in[0];
    const float* w_ih = (const float*)d_in[1];
    const float* w_hh = (const float*)d_in[2];
    const float* b_ih = (const float*)d_in[3];
    const float* b_hh = (const float*)d_in[4];
    const float* ca_w = (const float*)d_in[5];
    const float* ca_b = (const float*)d_in[6];
    float* out = (float*)d_out;
    float* ws  = (float*)d_ws;

    (void)hipFuncSetAttribute((const void*)persist_k,
                              hipFuncAttributeMaxDynamicSharedMemorySize, LDS_BYTES);
    hipLaunchKernelGGL(zero_ws_k, dim3(64), dim3(256), 0, stream, (unsigned*)ws);
    hipLaunchKernelGGL(persist_k, dim3(256), dim3(512), LDS_BYTES, stream,
                       x, w_ih, w_hh, b_ih, b_hh, ca_w, ca_b, out, ws);
}

// Round 4
// 3158.000 us; speedup vs baseline: 8.2904x; 3.0741x over previous
//
#include <hip/hip_runtime.h>
#include <math.h>

// ============================================================================
// StackedLSTM persistent-kernel R4.
// R3 post-mortem: barrier algorithm fixed but still 18.9 us/tick with all
// pipes ~95% idle -> residual cost is (a) two full __threadfence (buffer_wbl2
// L2 writebacks) per block per tick, (b) global-barrier lockstep amplifying
// per-block jitter. R4:
//   - h/c published via relaxed AGENT-scope atomic stores (write-through, no
//     dirty L2) -> release = s_waitcnt vmcnt(0) + flag store. No wbl2 at all.
//     One acquire fence (buffer_inv only) per tick.
//   - layered flag protocol replaces the global barrier:
//       WAIT-A (pre-stage):  flags[l][*] >= tau, flags[l-1][*] >= tau   (RAW)
//       WAIT-B (pre-store):  flags[l+1][*] >= tau                       (WAR)
//     WAIT-B is normally pre-satisfied -> slack between layers.
//   - x prefetched to VGPRs before WAIT-A; c_prev/c_low prefetched right
//     after; biases hoisted to registers.
// Compute structure (stage->MFMA 8-way K-split->LDS reduce->gates) unchanged
// from R3 (numerics identical, absmax 0.25 expected).
//
// ws word layout:
//   [0,      65536)  hws  f16[4][2][32][512]  (stored as packed u32 pairs)
//   [65536, 196608)  cws  f32[4][2][32][512]
//   [196608,197632)  flags[4][64][4]  (16B stride per block slot)
// ============================================================================

#define TT 512
#define HH 512
#define ROWP 1032                    // padded LDS row length in f16
#define W_OFF 0
#define A_OFF 82560                  // 40*ROWP*2
#define RED_OFF A_OFF                // aliases A region (used after dots done)
#define MF_OFF (A_OFF + 49152)       // after red[8][48][32] f32
#define LDS_BYTES (A_OFF + 66048)    // 148608 B -> 1 block/CU

#define CWS_OFF 65536
#define FL_OFF  196608
#define WS_ZERO_WORDS (FL_OFF + 1024)

typedef _Float16 half8 __attribute__((ext_vector_type(8)));
typedef float f32x4 __attribute__((ext_vector_type(4)));

__global__ void zero_ws_k(unsigned* __restrict__ ws){
    int i = blockIdx.x*blockDim.x + threadIdx.x;
    for (; i < WS_ZERO_WORDS; i += gridDim.x*blockDim.x) ws[i] = 0u;
}

__device__ __forceinline__ float sigm(float v){ return 1.f/(1.f+__expf(-v)); }

// Wave-cooperative poll: lane i watches flags[L][i] until all >= need.
__device__ __forceinline__ void poll_layer(const unsigned* fl, int L, unsigned need){
    const int i = threadIdx.x & 63;
    const unsigned* p = fl + (L*64 + i)*4;
    for (;;){
        const unsigned v = __hip_atomic_load(p, __ATOMIC_RELAXED, __HIP_MEMORY_SCOPE_AGENT);
        if (__all((int)(v >= need))) break;
        __builtin_amdgcn_s_sleep(2);
    }
}

// MT=2: layer 0 (LSTM, 32 gate-cols). MT=3: CALSTM (40 cols, rows 40-47 junk).
template<int MT>
__device__ void run_loop(const float* __restrict__ x, const float* __restrict__ b_ih,
                         const float* __restrict__ b_hh, const float* __restrict__ ca_b,
                         float* __restrict__ out, float* __restrict__ ws_f,
                         char* lds, int layer, int ub)
{
    const int tid  = threadIdx.x;
    const int lane = tid & 63;
    const int wv   = tid >> 6;              // wave id 0..7 = K-eighth
    const int i16  = lane & 15, qq = lane >> 4;
    unsigned short* hws = (unsigned short*)ws_f;   // f16[l][p][b][512]
    float*    cws = ws_f + CWS_OFF;                // f32[l][p][b][512]
    unsigned* fl  = (unsigned*)ws_f + FL_OFF;

    // gate-thread invariants (tid<256): unit gu, batch gb, global unit gj
    const int gu = tid & 7, gb = tid >> 3, gj = ub*8 + gu;
    float bias[5] = {0,0,0,0,0};
    if (tid < 256){
        if (MT == 2){
#pragma unroll
            for (int g = 0; g < 4; ++g) bias[g] = b_ih[g*512+gj] + b_hh[g*512+gj];
        } else {
            const float* cbl = ca_b + (layer-1)*2560;
#pragma unroll
            for (int g = 0; g < 5; ++g) bias[g] = cbl[g*512+gj];
            bias[1] += 1.f; bias[2] += 1.f;   // fold the +1.0 of f_prev/f_low
        }
    }
    // initial publish: idle ticks 0..layer-1 are vacuously complete
    if (tid == 0 && layer > 0)
        __hip_atomic_store(fl + (layer*64+ub)*4, (unsigned)layer,
                           __ATOMIC_RELAXED, __HIP_MEMORY_SCOPE_AGENT);

    for (int tau = layer; tau < TT + layer; ++tau){
        const int t = tau - layer;
        const int p = tau & 1, q = p ^ 1;

        // ---- x prefetch (layer 0, x-half threads) — no dependency on flags
        uint4 xpk[8];
        if (MT == 2 && (tid & 127) < 64){
#pragma unroll
            for (int it = 0; it < 8; ++it){
                const int cidx = tid + it*512;
                const int b = cidx >> 7, kc = (cidx & 127) << 3;   // kc < 512
                const float* xs = x + ((size_t)b*TT + t)*HH + kc;
                const float4 a = *(const float4*)xs;
                const float4 c = *(const float4*)(xs + 4);
                union { _Float16 h[8]; uint4 u; } pk;
                pk.h[0]=(_Float16)a.x; pk.h[1]=(_Float16)a.y;
                pk.h[2]=(_Float16)a.z; pk.h[3]=(_Float16)a.w;
                pk.h[4]=(_Float16)c.x; pk.h[5]=(_Float16)c.y;
                pk.h[6]=(_Float16)c.z; pk.h[7]=(_Float16)c.w;
                xpk[it] = pk.u;
            }
        }

        // ---- WAIT-A: producers of tick tau-1 (RAW) ----
        if (wv == 0)                    poll_layer(fl, layer,   (unsigned)tau);
        else if (wv == 1 && MT == 3)    poll_layer(fl, layer-1, (unsigned)tau);
        if (wv == 0) __builtin_amdgcn_fence(__ATOMIC_ACQUIRE, "agent"); // inv only
        __syncthreads();

        // ---- c prefetch for gate phase (fresh after inv, used much later)
        float cpv = 0.f, clov = 0.f;
        if (tid < 256){
            cpv = cws[(layer*2+q)*16384 + gb*512 + gj];
            if (MT == 3) clov = cws[((layer-1)*2+q)*16384 + gb*512 + gj];
        }

        // ---- stage A = [x_t | h_low ; h_prev] into LDS (f16) ----
        if (MT == 2){
            if ((tid & 127) < 64){
#pragma unroll
                for (int it = 0; it < 8; ++it){
                    const int cidx = tid + it*512;
                    const int b = cidx >> 7, kc = (cidx & 127) << 3;
                    *(uint4*)(lds + A_OFF + (size_t)(b*ROWP + kc)*2) = xpk[it];
                }
            } else {
                const unsigned short* hprev = hws + (layer*2+q)*16384;
#pragma unroll
                for (int it = 0; it < 8; ++it){
                    const int cidx = tid + it*512;
                    const int b = cidx >> 7, kc = (cidx & 127) << 3;  // kc>=512
                    const uint4 v = *(const uint4*)(hprev + b*512 + (kc - 512));
                    *(uint4*)(lds + A_OFF + (size_t)(b*ROWP + kc)*2) = v;
                }
            }
        } else {
            const unsigned short* hlow  = hws + ((layer-1)*2+q)*16384;
            const unsigned short* hprev = hws + (layer*2+q)*16384;
#pragma unroll
            for (int it = 0; it < 8; ++it){
                const int cidx = tid + it*512;
                const int b = cidx >> 7, kc = (cidx & 127) << 3;
                const uint4 v = (kc < 512) ? *(const uint4*)(hlow  + b*512 + kc)
                                           : *(const uint4*)(hprev + b*512 + (kc - 512));
                *(uint4*)(lds + A_OFF + (size_t)(b*ROWP + kc)*2) = v;
            }
        }
        __syncthreads();

        // ---- MFMA dots: this wave covers K-range [wv*128, wv*128+128) ----
        f32x4 acc[MT][2];
#pragma unroll
        for (int mt = 0; mt < MT; ++mt){ acc[mt][0] = (f32x4){0,0,0,0}; acc[mt][1] = (f32x4){0,0,0,0}; }
#pragma unroll
        for (int s = 0; s < 4; ++s){
            const int koff = wv*128 + s*32 + qq*8;
            half8 bfrag0 = *(const half8*)(lds + A_OFF + ((0*16 + i16)*ROWP + koff)*2);
            half8 bfrag1 = *(const half8*)(lds + A_OFF + ((1*16 + i16)*ROWP + koff)*2);
#pragma unroll
            for (int mt = 0; mt < MT; ++mt){
                half8 afrag = *(const half8*)(lds + W_OFF + ((mt*16 + i16)*ROWP + koff)*2);
                acc[mt][0] = __builtin_amdgcn_mfma_f32_16x16x32_f16(afrag, bfrag0, acc[mt][0], 0, 0, 0);
                acc[mt][1] = __builtin_amdgcn_mfma_f32_16x16x32_f16(afrag, bfrag1, acc[mt][1], 0, 0, 0);
            }
        }
        __syncthreads();            // A reads done; RED aliases A

        // ---- write K-partials: red[kq=wv][m][n] ----
#pragma unroll
        for (int mt = 0; mt < MT; ++mt)
#pragma unroll
            for (int nt = 0; nt < 2; ++nt)
#pragma unroll
                for (int r = 0; r < 4; ++r){
                    const int m = mt*16 + qq*4 + r, n = nt*16 + i16;
                    *(float*)(lds + RED_OFF + ((wv*48 + m)*32 + n)*4) = acc[mt][nt][r];
                }
        __syncthreads();

        // ---- reduce 8 partials -> mfinal[m][n] ----
        const int rows = (MT == 2) ? 32 : 40;
        for (int o = tid; o < rows*32; o += 512){
            const int m = o >> 5, n = o & 31;
            float sm = 0.f;
#pragma unroll
            for (int kq = 0; kq < 8; ++kq)
                sm += *(float*)(lds + RED_OFF + ((kq*48 + m)*32 + n)*4);
            *(float*)(lds + MF_OFF + o*4) = sm;
        }
        __syncthreads();

        // ---- gate phase (compute only) ----
        float hval = 0.f, cval = 0.f;
        if (tid < 256){
            const float* mf = (const float*)(lds + MF_OFF);
            if (MT == 2){
                const float mi  = mf[(0*8+gu)*32 + gb] + bias[0];
                const float mff = mf[(1*8+gu)*32 + gb] + bias[1];
                const float mg  = mf[(2*8+gu)*32 + gb] + bias[2];
                const float mo  = mf[(3*8+gu)*32 + gb] + bias[3];
                cval = sigm(mi)*tanhf(mg) + sigm(mff)*cpv;
                hval = sigm(mo)*tanhf(cval);
            } else {
                const float mi  = mf[(0*8+gu)*32 + gb] + bias[0];
                const float mfp = mf[(1*8+gu)*32 + gb] + bias[1];
                const float mfl = mf[(2*8+gu)*32 + gb] + bias[2];
                const float mu  = mf[(3*8+gu)*32 + gb] + bias[3];
                const float mo  = mf[(4*8+gu)*32 + gb] + bias[4];
                cval = cpv*sigm(mfp) + clov*sigm(mfl) + tanhf(mu)*sigm(mi);
                hval = sigm(mo)*tanhf(cval);
            }
        }

        // ---- WAIT-B: consumer of tick tau-1 done reading (WAR) ----
        if (layer < 3){
            if (wv == 0) poll_layer(fl, layer+1, (unsigned)tau);
            __syncthreads();
        }

        // ---- publish h (packed f16x2, write-through) and c (f32) ----
        const float hnb = __shfl_down(hval, 1);
        if (tid < 256){
            __hip_atomic_store(&cws[(layer*2+p)*16384 + gb*512 + gj], cval,
                               __ATOMIC_RELAXED, __HIP_MEMORY_SCOPE_AGENT);
            if ((gu & 1) == 0){
                union { _Float16 h2[2]; unsigned u; } pk;
                pk.h2[0] = (_Float16)hval; pk.h2[1] = (_Float16)hnb;
                __hip_atomic_store((unsigned*)(hws + (layer*2+p)*16384 + gb*512 + gj),
                                   pk.u, __ATOMIC_RELAXED, __HIP_MEMORY_SCOPE_AGENT);
            }
        }
        asm volatile("s_waitcnt vmcnt(0)" ::: "memory");   // stores at coherence pt
        __syncthreads();
        if (tid == 0)
            __hip_atomic_store(fl + (layer*64+ub)*4, (unsigned)(tau + 1),
                               __ATOMIC_RELAXED, __HIP_MEMORY_SCOPE_AGENT);

        // ---- outputs (not consumed on-device; after publish, off crit path)
        if (layer == 3 && tid < 256){
            const size_t pos = ((size_t)gb*TT + t)*HH + gj;
            out[pos]           = hval;
            out[8388608 + pos] = cval;
            if (t == TT-1){
                out[16777216 + (size_t)gb*HH + gj] = hval;
                out[16793600 + (size_t)gb*HH + gj] = cval;
            }
        }
    }
    // cover all future waits by neighbors
    if (tid == 0)
        __hip_atomic_store(fl + (layer*64+ub)*4, 0x7FFFFFFFu,
                           __ATOMIC_RELAXED, __HIP_MEMORY_SCOPE_AGENT);
}

__global__ __launch_bounds__(512) void persist_k(
    const float* __restrict__ x, const float* __restrict__ w_ih,
    const float* __restrict__ w_hh, const float* __restrict__ b_ih,
    const float* __restrict__ b_hh, const float* __restrict__ ca_w,
    const float* __restrict__ ca_b, float* __restrict__ out,
    float* __restrict__ ws_f)
{
    extern __shared__ char lds[];
    const int bx = blockIdx.x;
    const int layer = bx >> 6, ub = bx & 63;
    const int tid = threadIdx.x;
    const int rows = (layer == 0) ? 32 : 40;

    // one-time: weights fp32 -> f16 into LDS. local row r=g*8+u maps to
    // global gate-matrix row g*512 + ub*8 + u.
    for (int idx = tid; idx < rows*256; idx += 512){
        const int r = idx >> 8, k4 = (idx & 255) * 4;
        const int g = r >> 3, u = r & 7;
        const int grow = g*512 + ub*8 + u;
        const float* src;
        if (layer == 0) src = (k4 < 512) ? (w_ih + (size_t)grow*512 + k4)
                                         : (w_hh + (size_t)grow*512 + (k4 - 512));
        else            src = ca_w + (size_t)(layer-1)*2560*1024 + (size_t)grow*1024 + k4;
        const float4 v = *(const float4*)src;
        union { _Float16 h[4]; uint2 u2; } pk;
        pk.h[0]=(_Float16)v.x; pk.h[1]=(_Float16)v.y;
        pk.h[2]=(_Float16)v.z; pk.h[3]=(_Float16)v.w;
        *(uint2*)(lds + W_OFF + ((size_t)(r*ROWP + k4))*2) = pk.u2;
    }
    // first WAIT-A's __syncthreads orders weight-load before MFMA use.
    if (layer == 0) run_loop<2>(x, b_ih, b_hh, ca_b, out, ws_f, lds, layer, ub);
    else            run_loop<3>(x, b_ih, b_hh, ca_b, out, ws_f, lds, layer, ub);
}

extern "C" void kernel_launch(void* const* d_in, const int* in_sizes, int n_in,
                              void* d_out, int out_size, void* d_ws, size_t ws_size,
                              hipStream_t stream)
{
    const float* x    = (const float*)d_in[0];
    const float* w_ih = (const float*)d_in[1];
    const float* w_hh = (const float*)d_in[2];
    const float* b_ih = (const float*)d_in[3];
    const float* b_hh = (const float*)d_in[4];
    const float* ca_w = (const float*)d_in[5];
    const float* ca_b = (const float*)d_in[6];
    float* out = (float*)d_out;
    float* ws  = (float*)d_ws;

    (void)hipFuncSetAttribute((const void*)persist_k,
                              hipFuncAttributeMaxDynamicSharedMemorySize, LDS_BYTES);
    hipLaunchKernelGGL(zero_ws_k, dim3(64), dim3(256), 0, stream, (unsigned*)ws);
    hipLaunchKernelGGL(persist_k, dim3(256), dim3(512), LDS_BYTES, stream,
                       x, w_ih, w_hh, b_ih, b_hh, ca_w, ca_b, out, ws);
}